// Round 12
// baseline (1879.006 us; speedup 1.0000x reference)
//
#include <hip/hip_runtime.h>
#include <hip/hip_bf16.h>
#include <cstdint>

#define VOCAB 28996
#define T_STEPS 1024
#define D_IN 256
#define HDIM 512

using f32x4 = __attribute__((ext_vector_type(4))) float;
using s16x8 = __attribute__((ext_vector_type(8))) short;

static __device__ __forceinline__ unsigned short f2bf(float f){
    unsigned u = __float_as_uint(f);
    u = u + 0x7FFFu + ((u >> 16) & 1u);   // round-to-nearest-even
    return (unsigned short)(u >> 16);
}

#define SENT_U 0x7FC00001u

// ---------------------------------------------------------------------------
// Kernel 1: init — 8 private hs copies: row 0 = h0, rows 1..1024 = sentinel;
// zero ctrl (8 padded rank counters + done flag). Re-runs every replay.
// ---------------------------------------------------------------------------
__global__ void init_hs_kernel(const float* __restrict__ h0, float* __restrict__ hs_priv,
                               unsigned* __restrict__ ctrl){
    const int col = threadIdx.x;          // 0..511
    const int row = blockIdx.x;           // 0..1024
    const int cpy = blockIdx.y;           // 0..7
    float v = (row == 0) ? h0[col] : __uint_as_float(SENT_U);
    hs_priv[((size_t)cpy * (T_STEPS + 1) + row) * HDIM + col] = v;
    if (row == 0 && cpy == 0 && col < 288) ctrl[col] = 0u;
}

// ---------------------------------------------------------------------------
// Kernel 2: xg = x @ w_ih^T + b_ih   ([1024 x 256] @ [256 -> 1536])  fp32
// ---------------------------------------------------------------------------
__global__ void xg_kernel(const float* __restrict__ x, const float* __restrict__ w_ih,
                          const float* __restrict__ b_ih, float* __restrict__ xg){
    __shared__ float xs[8][D_IN];
    const int tid = threadIdx.x;
    const int i   = blockIdx.x * 256 + tid;   // 0..1535
    const int t0  = blockIdx.y * 8;
    #pragma unroll
    for (int r = 0; r < 8; ++r)
        xs[r][tid] = x[(size_t)(t0 + r) * D_IN + tid];
    __syncthreads();

    float acc[8] = {0.f,0.f,0.f,0.f,0.f,0.f,0.f,0.f};
    const float* wrow = w_ih + (size_t)i * D_IN;
    for (int d = 0; d < D_IN; d += 4){
        float4 w4 = *(const float4*)(wrow + d);
        #pragma unroll
        for (int r = 0; r < 8; ++r){
            acc[r] += w4.x * xs[r][d]   + w4.y * xs[r][d+1]
                    + w4.z * xs[r][d+2] + w4.w * xs[r][d+3];
        }
    }
    const float b = b_ih[i];
    #pragma unroll
    for (int r = 0; r < 8; ++r)
        xg[(size_t)(t0 + r) * (3*HDIM) + i] = acc[r] + b;
}

// ---------------------------------------------------------------------------
// Kernel 3: GRU scan — per-XCD redundant clusters on PRIVATE hs buffers.
// r8-r11 floor diagnosis: nt polls don't allocate L2 and each step's lines are
// virgin -> every pre-publication poll round = MALL RTT, and the h-store is an
// L2 write-miss (MALL line fill) => ~4000cy/step. Fixes here:
//  * private hs per XCD: sync lines never leave the local L2.
//  * PRE-TOUCH row t+4 with plain loads each step (allocates local L2; loaded
//    values parked in sink VGPRs consumed only by the next poll's vmcnt(0),
//    so no waitcnt stall at issue). Stores write-hit; nt polls L2-hit.
//  * 84KB LDS pad -> exactly 1 WG/CU; waves_per_eu(2,2) keeps 48 weights
//    resident (r10-proven).
//  * first completed cluster sets agent done-flag after bulk-copying its
//    private hs -> shared hs (GEMM input); other clusters abort (best-effort
//    nt check every 256 spins; bounded timeout as backstop).
// ---------------------------------------------------------------------------
#define LDW(G, P, s) \
    float G##s##0 = (P)[128*s + 0], G##s##1 = (P)[128*s + 1], \
          G##s##2 = (P)[128*s + 2], G##s##3 = (P)[128*s + 3];
#define PINW(G, s) \
    asm volatile("" : "+v"(G##s##0), "+v"(G##s##1), "+v"(G##s##2), "+v"(G##s##3));

#define GS(s, hh) { \
    ar += R##s##0*hh.x + R##s##1*hh.y + R##s##2*hh.z + R##s##3*hh.w; \
    az += Z##s##0*hh.x + Z##s##1*hh.y + Z##s##2*hh.z + Z##s##3*hh.w; \
    an += N##s##0*hh.x + N##s##1*hh.y + N##s##2*hh.z + N##s##3*hh.w; }

#define PRETOUCH(ROWP) { \
    const float* pa_ = (ROWP) + 4*c; \
    const float* pb_ = (ROWP) + j; \
    asm volatile( \
        "global_load_dword %0, %5, off\n\t" \
        "global_load_dword %1, %5, off offset:512\n\t" \
        "global_load_dword %2, %5, off offset:1024\n\t" \
        "global_load_dword %3, %5, off offset:1536\n\t" \
        "global_load_dword %4, %6, off" \
        : "=&v"(p0), "=&v"(p1), "=&v"(p2), "=&v"(p3), "=&v"(p4) \
        : "v"(pa_), "v"(pb_) : "memory"); }

#define NTPOLL(H0,H1,H2,H3,HJ,LP,JP) \
    asm volatile( \
        "global_load_dwordx4 %0, %5, off nt\n\t" \
        "global_load_dwordx4 %1, %5, off offset:512 nt\n\t" \
        "global_load_dwordx4 %2, %5, off offset:1024 nt\n\t" \
        "global_load_dwordx4 %3, %5, off offset:1536 nt\n\t" \
        "global_load_dword   %4, %6, off nt\n\t" \
        "s_waitcnt vmcnt(0)" \
        : "=&v"(H0), "=&v"(H1), "=&v"(H2), "=&v"(H3), "=&v"(HJ) \
        : "v"(LP), "v"(JP), "v"(p0), "v"(p1), "v"(p2), "v"(p3), "v"(p4) \
        : "memory")

#define SENTOK(H0,H1,H2,H3,HJ) \
      ((__float_as_uint(H0.x) != SENT_U) & (__float_as_uint(H0.y) != SENT_U) \
     & (__float_as_uint(H0.z) != SENT_U) & (__float_as_uint(H0.w) != SENT_U) \
     & (__float_as_uint(H1.x) != SENT_U) & (__float_as_uint(H1.y) != SENT_U) \
     & (__float_as_uint(H1.z) != SENT_U) & (__float_as_uint(H1.w) != SENT_U) \
     & (__float_as_uint(H2.x) != SENT_U) & (__float_as_uint(H2.y) != SENT_U) \
     & (__float_as_uint(H2.z) != SENT_U) & (__float_as_uint(H2.w) != SENT_U) \
     & (__float_as_uint(H3.x) != SENT_U) & (__float_as_uint(H3.y) != SENT_U) \
     & (__float_as_uint(H3.z) != SENT_U) & (__float_as_uint(H3.w) != SENT_U) \
     & (__float_as_uint(HJ)   != SENT_U))

__launch_bounds__(512)
__attribute__((amdgpu_waves_per_eu(2, 2)))
__global__ void scan_kernel(const float* __restrict__ xg, const float* __restrict__ w_hh,
                            const float* __restrict__ b_hh, float* hs_sh,
                            float* hs_priv, unsigned* ctrl){
    __shared__ volatile float lds_pad[21000];   // 84KB -> exactly 1 WG/CU
    __shared__ unsigned sh_rank, sh_xcc;

    const int tid = threadIdx.x;
    lds_pad[tid] = 0.f;                         // keep the pad allocated
    if (tid == 0){
        unsigned xcc;
        asm volatile("s_getreg_b32 %0, hwreg(HW_REG_XCC_ID)" : "=s"(xcc));
        xcc &= 7u;
        sh_xcc  = xcc;
        sh_rank = __hip_atomic_fetch_add(&ctrl[xcc * 32], 1u, __ATOMIC_RELAXED,
                                         __HIP_MEMORY_SCOPE_AGENT);
    }
    __syncthreads();
    const unsigned rank = sh_rank;
    if (rank >= 32u) return;                    // uniform per WG

    float* hsx = hs_priv + (size_t)sh_xcc * (T_STEPS + 1) * HDIM;
    const unsigned* donep = ctrl + 256;         // own 128B line

    const int c  = tid & 31;                    // column-chunk selector 0..31
    const int jl = tid >> 5;                    // 0..15
    const int j  = (int)rank * 16 + jl;         // 0..511

    // -- recurrent weights: 48 floats/thread -> resident VGPRs --
    const float* wrp = w_hh + (size_t)j * HDIM + 4*c;
    const float* wzp = w_hh + (size_t)(HDIM   + j) * HDIM + 4*c;
    const float* wnp = w_hh + (size_t)(2*HDIM + j) * HDIM + 4*c;
    LDW(R, wrp, 0) LDW(R, wrp, 1) LDW(R, wrp, 2) LDW(R, wrp, 3)
    LDW(Z, wzp, 0) LDW(Z, wzp, 1) LDW(Z, wzp, 2) LDW(Z, wzp, 3)
    LDW(N, wnp, 0) LDW(N, wnp, 1) LDW(N, wnp, 2) LDW(N, wnp, 3)
    PINW(R,0) PINW(R,1) PINW(R,2) PINW(R,3)
    PINW(Z,0) PINW(Z,1) PINW(Z,2) PINW(Z,3)
    PINW(N,0) PINW(N,1) PINW(N,2) PINW(N,3)

    float bhr = b_hh[j], bhz = b_hh[HDIM + j], bhn = b_hh[2*HDIM + j];
    asm volatile("" : "+v"(bhr), "+v"(bhz), "+v"(bhn));

    // xg pipeline register
    float xr_c = 0.f, xz_c = 0.f, xn_c = 0.f;
    if (c == 0){ xr_c = xg[j]; xz_c = xg[HDIM + j]; xn_c = xg[2*HDIM + j]; }

    // -- prologue pre-touch: rows 0..2 (consumed), row 3 into sink regs --
    {
        float s = 0.f;
        #pragma unroll
        for (int r = 0; r < 3; ++r){
            const float* pp = hsx + (size_t)r * HDIM;
            s += pp[4*c] + pp[4*c + 128] + pp[4*c + 256] + pp[4*c + 384] + pp[j];
        }
        asm volatile("" :: "v"(s));
    }
    float p0, p1, p2, p3, p4;
    { const float* pp = hsx + (size_t)3 * HDIM; PRETOUCH(pp); }

    const float* lanep = hsx + 4*c;
    const float* jp    = hsx + j;

    #pragma unroll 1
    for (int t = 0; t < T_STEPS; ++t){
        // ---- detect h_t: nt poll (bypasses L1; hits pre-touched local L2) ----
        f32x4 h0, h1, h2, h3;
        float hj;
        int spins = 0;
        for (;;){
            NTPOLL(h0, h1, h2, h3, hj, lanep, jp);
            int ok = SENTOK(h0, h1, h2, h3, hj);
            if (__all(ok)) break;               // wave-uniform
            if ((++spins & 255) == 0){          // best-effort abort + timeout
                unsigned dn;
                asm volatile("global_load_dword %0, %1, off nt\n\ts_waitcnt vmcnt(0)"
                             : "=&v"(dn) : "v"(donep) : "memory");
                if (__any(dn != 0)) return;     // another cluster finished
                if (spins > 6000) return;       // dead-cluster backstop
            }
        }

        // ---- pre-touch row t+4 into local L2 (plain; sunk into next poll) ----
        if (t + 4 <= T_STEPS){
            const float* pp = hsx + (size_t)(t + 4) * HDIM;
            PRETOUCH(pp);
        }

        // ---- xg prefetch for t+1 (hides under compute) ----
        float xr_n = 0.f, xz_n = 0.f, xn_n = 0.f;
        if (c == 0 && t + 1 < T_STEPS){
            const float* xgn = xg + (size_t)(t + 1) * (3*HDIM);
            xr_n = xgn[j]; xz_n = xgn[HDIM + j]; xn_n = xgn[2*HDIM + j];
        }

        // ---- partial matvec: 48 FMAs, reduce over c=0..31, gates, store ----
        float ar = 0.f, az = 0.f, an = 0.f;
        GS(0, h0) GS(1, h1) GS(2, h2) GS(3, h3)
        #pragma unroll
        for (int m = 1; m < 32; m <<= 1){
            ar += __shfl_xor(ar, m);
            az += __shfl_xor(az, m);
            an += __shfl_xor(an, m);
        }
        if (c == 0){
            const float r  = 1.0f / (1.0f + __expf(-(xr_c + ar + bhr)));
            const float z  = 1.0f / (1.0f + __expf(-(xz_c + az + bhz)));
            const float nn = xn_c + r * (an + bhn);
            const float e  = __expf(2.0f * nn);
            const float th = 1.0f - 2.0f / (e + 1.0f);   // tanh, inf-safe
            const float hnew = (1.0f - z) * th + z * hj;
            hsx[(size_t)(t + 1) * HDIM + j] = hnew;      // write-hit; IS the flag
        }
        xr_c = xr_n; xz_c = xz_n; xn_c = xn_n;
        lanep += HDIM; jp += HDIM;
    }

    // ---- final detect: row T_STEPS complete (stores by the other WGs) ----
    {
        f32x4 a0, a1, a2, a3; float aj;
        int spins = 0;
        for (;;){
            NTPOLL(a0, a1, a2, a3, aj, lanep, jp);
            int ok = SENTOK(a0, a1, a2, a3, aj);
            if (__all(ok)) break;
            if (++spins > 6000) return;
        }
    }

    // ---- bulk-copy rows 1..1024 private -> shared (nt loads beat stale L1) ----
    {
        const int p = (int)rank * 512 + tid;   // 0..16383; 8 float4 each
        #pragma unroll
        for (int k = 0; k < 8; k += 2){
            const size_t i0 = 128 + (size_t)p + (size_t)k * 16384;
            const size_t i1 = i0 + 16384;
            const float* s0 = (const float*)hsx + i0 * 4;
            const float* s1 = (const float*)hsx + i1 * 4;
            f32x4 v0, v1;
            asm volatile("global_load_dwordx4 %0, %2, off nt\n\t"
                         "global_load_dwordx4 %1, %3, off nt\n\t"
                         "s_waitcnt vmcnt(0)"
                         : "=&v"(v0), "=&v"(v1) : "v"(s0), "v"(s1) : "memory");
            *(f32x4*)((float*)hs_sh + i0 * 4) = v0;
            *(f32x4*)((float*)hs_sh + i1 * 4) = v1;
        }
    }
    // signal completion (agent scope -> visible to all XCDs)
    if (tid == 0)
        __hip_atomic_store((unsigned*)donep, 1u, __ATOMIC_RELAXED,
                           __HIP_MEMORY_SCOPE_AGENT);
}

// ---------------------------------------------------------------------------
// Kernel 4: preds = hs[1..1024] @ w_pred^T + b_pred  (bf16 MFMA, fp32 out)
// ---------------------------------------------------------------------------
__launch_bounds__(256)
__global__ void pred_gemm_kernel(const float* __restrict__ hs, const float* __restrict__ w_pred,
                                 const float* __restrict__ b_pred, float* __restrict__ out){
    __shared__ unsigned short As[128 * 32];
    __shared__ unsigned short Bs[128 * 32];
    const int tid   = threadIdx.x;
    const int mtile = blockIdx.x;    // 0..7
    const int ntile = blockIdx.y;    // 0..226
    const int row  = tid >> 1, half = tid & 1;
    const int wave = tid >> 6, lane = tid & 63;
    const int wm = wave >> 1, wn = wave & 1;
    const int lr = lane & 15, kq = lane >> 4;

    f32x4 acc[4][4] = {};

    const float* Abase = hs + HDIM /*skip h0 row*/ + (size_t)(mtile * 128 + row) * HDIM;
    const int    nrow  = ntile * 128 + row;
    const float* Bbase = w_pred + (size_t)nrow * HDIM;

    for (int k0 = 0; k0 < HDIM; k0 += 32){
        {
            const float* srcp = Abase + k0 + half * 16;
            unsigned short* dst = &As[row * 32 + half * 16];
            #pragma unroll
            for (int q = 0; q < 4; ++q){
                float4 v = *(const float4*)(srcp + 4 * q);
                uint2 p;
                p.x = (unsigned)f2bf(v.x) | ((unsigned)f2bf(v.y) << 16);
                p.y = (unsigned)f2bf(v.z) | ((unsigned)f2bf(v.w) << 16);
                *(uint2*)(dst + 4 * q) = p;
            }
        }
        {
            unsigned short* dst = &Bs[row * 32 + half * 16];
            if (nrow < VOCAB){
                const float* srcp = Bbase + k0 + half * 16;
                #pragma unroll
                for (int q = 0; q < 4; ++q){
                    float4 v = *(const float4*)(srcp + 4 * q);
                    uint2 p;
                    p.x = (unsigned)f2bf(v.x) | ((unsigned)f2bf(v.y) << 16);
                    p.y = (unsigned)f2bf(v.z) | ((unsigned)f2bf(v.w) << 16);
                    *(uint2*)(dst + 4 * q) = p;
                }
            } else {
                uint2 zz; zz.x = 0u; zz.y = 0u;
                #pragma unroll
                for (int q = 0; q < 4; ++q) *(uint2*)(dst + 4 * q) = zz;
            }
        }
        __syncthreads();

        const unsigned short* Ab = &As[(wm * 64 + lr) * 32 + kq * 8];
        const unsigned short* Bb = &Bs[(wn * 64 + lr) * 32 + kq * 8];
        s16x8 af[4], bf[4];
        #pragma unroll
        for (int mf = 0; mf < 4; ++mf) af[mf] = *(const s16x8*)(Ab + mf * 16 * 32);
        #pragma unroll
        for (int nf = 0; nf < 4; ++nf) bf[nf] = *(const s16x8*)(Bb + nf * 16 * 32);
        #pragma unroll
        for (int mf = 0; mf < 4; ++mf){
            #pragma unroll
            for (int nf = 0; nf < 4; ++nf){
                acc[mf][nf] = __builtin_amdgcn_mfma_f32_16x16x32_bf16(af[mf], bf[nf], acc[mf][nf], 0, 0, 0);
            }
        }
        __syncthreads();
    }

    #pragma unroll
    for (int nf = 0; nf < 4; ++nf){
        const int n = ntile * 128 + wn * 64 + nf * 16 + lr;
        if (n >= VOCAB) continue;
        const float bp = b_pred[n];
        #pragma unroll
        for (int mf = 0; mf < 4; ++mf){
            const int m = mtile * 128 + wm * 64 + mf * 16 + kq * 4;
            #pragma unroll
            for (int q = 0; q < 4; ++q){
                out[(size_t)(m + q) * VOCAB + n] = acc[mf][nf][q] + bp;
            }
        }
    }
}

// ---------------------------------------------------------------------------
extern "C" void kernel_launch(void* const* d_in, const int* in_sizes, int n_in,
                              void* d_out, int out_size, void* d_ws, size_t ws_size,
                              hipStream_t stream){
    const float* x      = (const float*)d_in[0];
    const float* h0     = (const float*)d_in[1];
    const float* w_ih   = (const float*)d_in[2];
    const float* w_hh   = (const float*)d_in[3];
    const float* b_ih   = (const float*)d_in[4];
    const float* b_hh   = (const float*)d_in[5];
    const float* w_pred = (const float*)d_in[6];
    const float* b_pred = (const float*)d_in[7];
    float* out = (float*)d_out;

    float*    xg      = (float*)d_ws;                                  // 1.57M f
    float*    hs_sh   = xg + (size_t)T_STEPS * (3*HDIM);               // 525K f
    float*    hs_priv = hs_sh + (size_t)(T_STEPS + 1) * HDIM;          // 8x525K f
    unsigned* ctrl    = (unsigned*)(hs_priv + 8 * (size_t)(T_STEPS + 1) * HDIM); // 288 u32

    hipLaunchKernelGGL(init_hs_kernel, dim3(T_STEPS + 1, 8), dim3(HDIM), 0, stream, h0, hs_priv, ctrl);
    hipLaunchKernelGGL(xg_kernel,      dim3(6, 128),         dim3(256), 0, stream, x, w_ih, b_ih, xg);
    hipLaunchKernelGGL(scan_kernel,    dim3(256),            dim3(512), 0, stream, xg, w_hh, b_hh, hs_sh, hs_priv, ctrl);
    hipLaunchKernelGGL(pred_gemm_kernel, dim3(8, 227),       dim3(256), 0, stream, hs_sh, w_pred, b_pred, out);
}

// Round 13
// 1665.249 us; speedup vs baseline: 1.1284x; 1.1284x over previous
//
#include <hip/hip_runtime.h>
#include <hip/hip_bf16.h>
#include <cstdint>

#define VOCAB 28996
#define T_STEPS 1024
#define D_IN 256
#define HDIM 512

using f32x4 = __attribute__((ext_vector_type(4))) float;
using s16x8 = __attribute__((ext_vector_type(8))) short;

static __device__ __forceinline__ unsigned short f2bf(float f){
    unsigned u = __float_as_uint(f);
    u = u + 0x7FFFu + ((u >> 16) & 1u);   // round-to-nearest-even
    return (unsigned short)(u >> 16);
}

#define SENT_U 0x7FC00001u

// ---------------------------------------------------------------------------
// Kernel 1: init — hs row 0 = h0, rows 1..1024 = NaN sentinel; zero rank ctrs
// ---------------------------------------------------------------------------
__global__ void init_hs_kernel(const float* __restrict__ h0, float* __restrict__ hs,
                               unsigned* __restrict__ ctrl){
    const int col = threadIdx.x;          // 0..511
    const int row = blockIdx.x;           // 0..1024
    float v = (row == 0) ? h0[col] : __uint_as_float(SENT_U);
    hs[(size_t)row * HDIM + col] = v;
    if (row == 0 && col < 8) ctrl[col] = 0u;
}

// ---------------------------------------------------------------------------
// Kernel 2: xg = x @ w_ih^T + b_ih   ([1024 x 256] @ [256 -> 1536])  fp32
// ---------------------------------------------------------------------------
__global__ void xg_kernel(const float* __restrict__ x, const float* __restrict__ w_ih,
                          const float* __restrict__ b_ih, float* __restrict__ xg){
    __shared__ float xs[8][D_IN];
    const int tid = threadIdx.x;
    const int i   = blockIdx.x * 256 + tid;   // 0..1535
    const int t0  = blockIdx.y * 8;
    #pragma unroll
    for (int r = 0; r < 8; ++r)
        xs[r][tid] = x[(size_t)(t0 + r) * D_IN + tid];
    __syncthreads();

    float acc[8] = {0.f,0.f,0.f,0.f,0.f,0.f,0.f,0.f};
    const float* wrow = w_ih + (size_t)i * D_IN;
    for (int d = 0; d < D_IN; d += 4){
        float4 w4 = *(const float4*)(wrow + d);
        #pragma unroll
        for (int r = 0; r < 8; ++r){
            acc[r] += w4.x * xs[r][d]   + w4.y * xs[r][d+1]
                    + w4.z * xs[r][d+2] + w4.w * xs[r][d+3];
        }
    }
    const float b = b_ih[i];
    #pragma unroll
    for (int r = 0; r < 8; ++r)
        xg[(size_t)(t0 + r) * (3*HDIM) + i] = acc[r] + b;
}

// ---------------------------------------------------------------------------
// Kernel 3: GRU scan — r8's proven structure (best measured: 1.61us/step)
// with two fixes:
//  * amdgpu_waves_per_eu(2,2): 256-VGPR budget -> the 96 weight floats are
//    actually register-resident (r8 ran at VGPR=76 = scratch-spilled; r10
//    proved the attribute fixes residency).
//  * s_waitcnt vmcnt(0) at END of loop body: forces the h-store to drain to
//    the XCD L2 immediately (visibility starts during our own slack) and
//    lands the t+1 xg prefetch registers, so the next poll's vmcnt(0) never
//    inherits a pending HBM/MALL load (r8 stalled ~300-500cy/step on this).
// Protocol unchanged (r8-proven): per-wave NT poll of the sentinel row
// (nt = no L1 allocate -> always-fresh XCD-L2 read), per-wave LDS staging,
// plain write-through store IS the flag. Zero atomics/barriers in the loop.
// Redundant per-XCD clusters; dead clusters exit on bounded wave-uniform
// timeout; >=1 complete cluster by pigeonhole; identical writes -> benign.
// ---------------------------------------------------------------------------
#define LDW(G, P, n) \
    float G##n##0 = (P)[64*n + 0], G##n##1 = (P)[64*n + 1], \
          G##n##2 = (P)[64*n + 2], G##n##3 = (P)[64*n + 3];
#define PINW(G, n) \
    asm volatile("" : "+v"(G##n##0), "+v"(G##n##1), "+v"(G##n##2), "+v"(G##n##3));

#define GSTEP(n, arx, azx, anx) { \
    float4 h4 = *(const float4*)&hbuf[wv][4*c + 64*n]; \
    arx += R##n##0*h4.x + R##n##1*h4.y + R##n##2*h4.z + R##n##3*h4.w; \
    azx += Z##n##0*h4.x + Z##n##1*h4.y + Z##n##2*h4.z + Z##n##3*h4.w; \
    anx += N##n##0*h4.x + N##n##1*h4.y + N##n##2*h4.z + N##n##3*h4.w; }

__launch_bounds__(512)
__attribute__((amdgpu_waves_per_eu(2, 2)))
__global__ void scan_kernel(const float* __restrict__ xg, const float* __restrict__ w_hh,
                            const float* __restrict__ b_hh, float* hs, unsigned* ctrl){
    __shared__ __align__(16) float hbuf[8][HDIM];   // per-wave private row copy
    __shared__ unsigned sh_rank;

    const int tid = threadIdx.x;
    if (tid == 0){
        unsigned xcc;
        asm volatile("s_getreg_b32 %0, hwreg(HW_REG_XCC_ID)" : "=s"(xcc));
        sh_rank = __hip_atomic_fetch_add(&ctrl[xcc & 7u], 1u, __ATOMIC_RELAXED,
                                         __HIP_MEMORY_SCOPE_AGENT);
    }
    __syncthreads();
    const unsigned rank = sh_rank;
    if (rank >= 16u) return;              // uniform per WG

    const int wv   = tid >> 6;            // wave 0..7
    const int lane = tid & 63;
    const int c    = tid & 15;            // column-chunk selector 0..15
    const int jl   = tid >> 4;            // 0..31
    const int j    = (int)rank * 32 + jl; // 0..511

    // -- recurrent weights: 96 floats/thread -> resident VGPRs (256 budget) --
    const float* wrp = w_hh + (size_t)j * HDIM + 4*c;
    const float* wzp = w_hh + (size_t)(HDIM   + j) * HDIM + 4*c;
    const float* wnp = w_hh + (size_t)(2*HDIM + j) * HDIM + 4*c;
    LDW(R, wrp, 0) LDW(R, wrp, 1) LDW(R, wrp, 2) LDW(R, wrp, 3)
    LDW(R, wrp, 4) LDW(R, wrp, 5) LDW(R, wrp, 6) LDW(R, wrp, 7)
    LDW(Z, wzp, 0) LDW(Z, wzp, 1) LDW(Z, wzp, 2) LDW(Z, wzp, 3)
    LDW(Z, wzp, 4) LDW(Z, wzp, 5) LDW(Z, wzp, 6) LDW(Z, wzp, 7)
    LDW(N, wnp, 0) LDW(N, wnp, 1) LDW(N, wnp, 2) LDW(N, wnp, 3)
    LDW(N, wnp, 4) LDW(N, wnp, 5) LDW(N, wnp, 6) LDW(N, wnp, 7)
    PINW(R,0) PINW(R,1) PINW(R,2) PINW(R,3) PINW(R,4) PINW(R,5) PINW(R,6) PINW(R,7)
    PINW(Z,0) PINW(Z,1) PINW(Z,2) PINW(Z,3) PINW(Z,4) PINW(Z,5) PINW(Z,6) PINW(Z,7)
    PINW(N,0) PINW(N,1) PINW(N,2) PINW(N,3) PINW(N,4) PINW(N,5) PINW(N,6) PINW(N,7)

    float bhr = b_hh[j], bhz = b_hh[HDIM + j], bhn = b_hh[2*HDIM + j];
    asm volatile("" : "+v"(bhr), "+v"(bhz), "+v"(bhn));

    // xg pipeline register (t=0 filled here, re-filled each step)
    float xr_c = 0.f, xz_c = 0.f, xn_c = 0.f;
    if (c == 0){ xr_c = xg[j]; xz_c = xg[HDIM + j]; xn_c = xg[2*HDIM + j]; }

    #pragma unroll 1
    for (int t = 0; t < T_STEPS; ++t){
        // ---- detect h_t ready: NT-poll the row itself (detect == stage) ----
        const float4* myp = (const float4*)(hs + (size_t)t * HDIM) + lane;
        float4 va, vb;
        int spins = 0;
        for (;;){
            asm volatile("global_load_dwordx4 %0, %2, off nt\n\t"
                         "global_load_dwordx4 %1, %2, off offset:1024 nt\n\t"
                         "s_waitcnt vmcnt(0)"
                         : "=&v"(va), "=&v"(vb) : "v"(myp) : "memory");
            int ok = (__float_as_uint(va.x) != SENT_U) & (__float_as_uint(va.y) != SENT_U)
                   & (__float_as_uint(va.z) != SENT_U) & (__float_as_uint(va.w) != SENT_U)
                   & (__float_as_uint(vb.x) != SENT_U) & (__float_as_uint(vb.y) != SENT_U)
                   & (__float_as_uint(vb.z) != SENT_U) & (__float_as_uint(vb.w) != SENT_U);
            if (__all(ok)) break;         // wave-uniform
            if (++spins > 5000) return;   // wave-uniform timeout (dead cluster)
        }

        // ---- issue next step's xg loads (landed by end-of-loop vmcnt) ----
        float xr_n = 0.f, xz_n = 0.f, xn_n = 0.f;
        if (c == 0 && t + 1 < T_STEPS){
            const float* xgn = xg + (size_t)(t + 1) * (3*HDIM);
            xr_n = xgn[j]; xz_n = xgn[HDIM + j]; xn_n = xgn[2*HDIM + j];
        }

        // ---- stage to this wave's LDS row (contiguous 16B/lane) ----
        *(float4*)&hbuf[wv][4 * lane]       = va;
        *(float4*)&hbuf[wv][256 + 4 * lane] = vb;
        asm volatile("s_waitcnt lgkmcnt(0)" ::: "memory");
        __builtin_amdgcn_sched_barrier(0);

        // ---- partial matvec: 96 FMAs/lane, 6 independent chains ----
        float ar0=0.f, ar1=0.f, az0=0.f, az1=0.f, an0=0.f, an1=0.f;
        GSTEP(0, ar0, az0, an0)  GSTEP(1, ar1, az1, an1)
        GSTEP(2, ar0, az0, an0)  GSTEP(3, ar1, az1, an1)
        GSTEP(4, ar0, az0, an0)  GSTEP(5, ar1, az1, an1)
        GSTEP(6, ar0, az0, an0)  GSTEP(7, ar1, az1, an1)
        float ar = ar0 + ar1, az = az0 + az1, an = an0 + an1;
        #pragma unroll
        for (int m = 1; m < 16; m <<= 1){
            ar += __shfl_xor(ar, m);
            az += __shfl_xor(az, m);
            an += __shfl_xor(an, m);
        }

        if (c == 0){
            const float r  = 1.0f / (1.0f + __expf(-(xr_c + ar + bhr)));
            const float z  = 1.0f / (1.0f + __expf(-(xz_c + az + bhz)));
            const float nn = xn_c + r * (an + bhn);
            const float e  = __expf(2.0f * nn);
            const float th = 1.0f - 2.0f / (e + 1.0f);   // tanh, inf-safe
            const float hnew = (1.0f - z) * th + z * hbuf[wv][j];
            hs[(size_t)(t + 1) * HDIM + j] = hnew;   // write-through store IS the flag
        }
        // drain the h-store to L2 NOW (visibility clock starts here, in our
        // slack) and land the xg prefetch so the next poll inherits nothing.
        asm volatile("s_waitcnt vmcnt(0)" ::: "memory");

        xr_c = xr_n; xz_c = xz_n; xn_c = xn_n;
    }
}

// ---------------------------------------------------------------------------
// Kernel 4: preds = hs[1..1024] @ w_pred^T + b_pred  (bf16 MFMA, fp32 out)
// ---------------------------------------------------------------------------
__launch_bounds__(256)
__global__ void pred_gemm_kernel(const float* __restrict__ hs, const float* __restrict__ w_pred,
                                 const float* __restrict__ b_pred, float* __restrict__ out){
    __shared__ unsigned short As[128 * 32];
    __shared__ unsigned short Bs[128 * 32];
    const int tid   = threadIdx.x;
    const int mtile = blockIdx.x;    // 0..7
    const int ntile = blockIdx.y;    // 0..226
    const int row  = tid >> 1, half = tid & 1;
    const int wave = tid >> 6, lane = tid & 63;
    const int wm = wave >> 1, wn = wave & 1;
    const int lr = lane & 15, kq = lane >> 4;

    f32x4 acc[4][4] = {};

    const float* Abase = hs + HDIM /*skip h0 row*/ + (size_t)(mtile * 128 + row) * HDIM;
    const int    nrow  = ntile * 128 + row;
    const float* Bbase = w_pred + (size_t)nrow * HDIM;

    for (int k0 = 0; k0 < HDIM; k0 += 32){
        {
            const float* srcp = Abase + k0 + half * 16;
            unsigned short* dst = &As[row * 32 + half * 16];
            #pragma unroll
            for (int q = 0; q < 4; ++q){
                float4 v = *(const float4*)(srcp + 4 * q);
                uint2 p;
                p.x = (unsigned)f2bf(v.x) | ((unsigned)f2bf(v.y) << 16);
                p.y = (unsigned)f2bf(v.z) | ((unsigned)f2bf(v.w) << 16);
                *(uint2*)(dst + 4 * q) = p;
            }
        }
        {
            unsigned short* dst = &Bs[row * 32 + half * 16];
            if (nrow < VOCAB){
                const float* srcp = Bbase + k0 + half * 16;
                #pragma unroll
                for (int q = 0; q < 4; ++q){
                    float4 v = *(const float4*)(srcp + 4 * q);
                    uint2 p;
                    p.x = (unsigned)f2bf(v.x) | ((unsigned)f2bf(v.y) << 16);
                    p.y = (unsigned)f2bf(v.z) | ((unsigned)f2bf(v.w) << 16);
                    *(uint2*)(dst + 4 * q) = p;
                }
            } else {
                uint2 zz; zz.x = 0u; zz.y = 0u;
                #pragma unroll
                for (int q = 0; q < 4; ++q) *(uint2*)(dst + 4 * q) = zz;
            }
        }
        __syncthreads();

        const unsigned short* Ab = &As[(wm * 64 + lr) * 32 + kq * 8];
        const unsigned short* Bb = &Bs[(wn * 64 + lr) * 32 + kq * 8];
        s16x8 af[4], bf[4];
        #pragma unroll
        for (int mf = 0; mf < 4; ++mf) af[mf] = *(const s16x8*)(Ab + mf * 16 * 32);
        #pragma unroll
        for (int nf = 0; nf < 4; ++nf) bf[nf] = *(const s16x8*)(Bb + nf * 16 * 32);
        #pragma unroll
        for (int mf = 0; mf < 4; ++mf){
            #pragma unroll
            for (int nf = 0; nf < 4; ++nf){
                acc[mf][nf] = __builtin_amdgcn_mfma_f32_16x16x32_bf16(af[mf], bf[nf], acc[mf][nf], 0, 0, 0);
            }
        }
        __syncthreads();
    }

    #pragma unroll
    for (int nf = 0; nf < 4; ++nf){
        const int n = ntile * 128 + wn * 64 + nf * 16 + lr;
        if (n >= VOCAB) continue;
        const float bp = b_pred[n];
        #pragma unroll
        for (int mf = 0; mf < 4; ++mf){
            const int m = mtile * 128 + wm * 64 + mf * 16 + kq * 4;
            #pragma unroll
            for (int q = 0; q < 4; ++q){
                out[(size_t)(m + q) * VOCAB + n] = acc[mf][nf][q] + bp;
            }
        }
    }
}

// ---------------------------------------------------------------------------
extern "C" void kernel_launch(void* const* d_in, const int* in_sizes, int n_in,
                              void* d_out, int out_size, void* d_ws, size_t ws_size,
                              hipStream_t stream){
    const float* x      = (const float*)d_in[0];
    const float* h0     = (const float*)d_in[1];
    const float* w_ih   = (const float*)d_in[2];
    const float* w_hh   = (const float*)d_in[3];
    const float* b_ih   = (const float*)d_in[4];
    const float* b_hh   = (const float*)d_in[5];
    const float* w_pred = (const float*)d_in[6];
    const float* b_pred = (const float*)d_in[7];
    float* out = (float*)d_out;

    float*    xg   = (float*)d_ws;                        // 1024*1536 fp32
    float*    hs   = xg + (size_t)T_STEPS * (3*HDIM);     // 1025*512  fp32
    unsigned* ctrl = (unsigned*)(hs + (size_t)(T_STEPS+1) * HDIM);  // 8 u32

    hipLaunchKernelGGL(init_hs_kernel, dim3(T_STEPS + 1), dim3(HDIM), 0, stream, h0, hs, ctrl);
    hipLaunchKernelGGL(xg_kernel,      dim3(6, 128),      dim3(256),  0, stream, x, w_ih, b_ih, xg);
    hipLaunchKernelGGL(scan_kernel,    dim3(128),         dim3(512),  0, stream, xg, w_hh, b_hh, hs, ctrl);
    hipLaunchKernelGGL(pred_gemm_kernel, dim3(8, 227),    dim3(256),  0, stream, hs, w_pred, b_pred, out);
}

// Round 14
// 1567.326 us; speedup vs baseline: 1.1989x; 1.0625x over previous
//
#include <hip/hip_runtime.h>
#include <hip/hip_bf16.h>
#include <cstdint>

#define VOCAB 28996
#define T_STEPS 1024
#define D_IN 256
#define HDIM 512

using f32x4 = __attribute__((ext_vector_type(4))) float;
using s16x8 = __attribute__((ext_vector_type(8))) short;

static __device__ __forceinline__ unsigned short f2bf(float f){
    unsigned u = __float_as_uint(f);
    u = u + 0x7FFFu + ((u >> 16) & 1u);   // round-to-nearest-even
    return (unsigned short)(u >> 16);
}

#define SENT_U 0x7FC00001u

// ---------------------------------------------------------------------------
// Kernel 1: init — hs row 0 = h0, rows 1..1024 = NaN sentinel; zero rank ctrs
// ---------------------------------------------------------------------------
__global__ void init_hs_kernel(const float* __restrict__ h0, float* __restrict__ hs,
                               unsigned* __restrict__ ctrl){
    const int col = threadIdx.x;          // 0..511
    const int row = blockIdx.x;           // 0..1024
    float v = (row == 0) ? h0[col] : __uint_as_float(SENT_U);
    hs[(size_t)row * HDIM + col] = v;
    if (row == 0 && col < 8) ctrl[col] = 0u;
}

// ---------------------------------------------------------------------------
// Kernel 2: xg = x @ w_ih^T + b_ih   ([1024 x 256] @ [256 -> 1536])  fp32
// ---------------------------------------------------------------------------
__global__ void xg_kernel(const float* __restrict__ x, const float* __restrict__ w_ih,
                          const float* __restrict__ b_ih, float* __restrict__ xg){
    __shared__ float xs[8][D_IN];
    const int tid = threadIdx.x;
    const int i   = blockIdx.x * 256 + tid;   // 0..1535
    const int t0  = blockIdx.y * 8;
    #pragma unroll
    for (int r = 0; r < 8; ++r)
        xs[r][tid] = x[(size_t)(t0 + r) * D_IN + tid];
    __syncthreads();

    float acc[8] = {0.f,0.f,0.f,0.f,0.f,0.f,0.f,0.f};
    const float* wrow = w_ih + (size_t)i * D_IN;
    for (int d = 0; d < D_IN; d += 4){
        float4 w4 = *(const float4*)(wrow + d);
        #pragma unroll
        for (int r = 0; r < 8; ++r){
            acc[r] += w4.x * xs[r][d]   + w4.y * xs[r][d+1]
                    + w4.z * xs[r][d+2] + w4.w * xs[r][d+3];
        }
    }
    const float b = b_ih[i];
    #pragma unroll
    for (int r = 0; r < 8; ++r)
        xg[(size_t)(t0 + r) * (3*HDIM) + i] = acc[r] + b;
}

// ---------------------------------------------------------------------------
// Kernel 3: GRU scan — r13's proven protocol on the 48-weight partition.
// 32-WG clusters x 512 thr: 16 j/WG, 32 thr/j, 48 weight fp32/thread.
// Rationale: r10 proved 48 w/thread goes VGPR-resident at 88 (the allocator's
// observed cap for this kernel shape); r13's 96 w/thread stayed half-spilled
// (VGPR=88 < 96+operands). 48-w partition also halves per-CU FMA issue.
// Loop protocol (r13, best measured 1.51us/step): per-wave NT-poll of the
// sentinel row (nt = no L1 allocate -> always-fresh XCD-L2 read), per-wave
// LDS stage, write-through store IS the flag, single end-of-loop vmcnt(0)
// drains the h-store and lands the xg prefetch. Zero atomics/barriers.
// Redundant per-XCD clusters; dead clusters exit on bounded wave-uniform
// timeout; >=1 complete cluster by pigeonhole; identical writes -> benign.
// ---------------------------------------------------------------------------
#define LDW(G, P, s) \
    float G##s##0 = (P)[128*s + 0], G##s##1 = (P)[128*s + 1], \
          G##s##2 = (P)[128*s + 2], G##s##3 = (P)[128*s + 3];
#define PINW(G, s) \
    asm volatile("" : "+v"(G##s##0), "+v"(G##s##1), "+v"(G##s##2), "+v"(G##s##3));

#define GSTEP(s) { \
    float4 h4 = *(const float4*)&hbuf[wv][4*c + 128*s]; \
    ar += R##s##0*h4.x + R##s##1*h4.y + R##s##2*h4.z + R##s##3*h4.w; \
    az += Z##s##0*h4.x + Z##s##1*h4.y + Z##s##2*h4.z + Z##s##3*h4.w; \
    an += N##s##0*h4.x + N##s##1*h4.y + N##s##2*h4.z + N##s##3*h4.w; }

__launch_bounds__(512)
__attribute__((amdgpu_waves_per_eu(2, 2)))
__global__ void scan_kernel(const float* __restrict__ xg, const float* __restrict__ w_hh,
                            const float* __restrict__ b_hh, float* hs, unsigned* ctrl){
    __shared__ __align__(16) float hbuf[8][HDIM];   // per-wave private row copy
    __shared__ unsigned sh_rank;

    const int tid = threadIdx.x;
    if (tid == 0){
        unsigned xcc;
        asm volatile("s_getreg_b32 %0, hwreg(HW_REG_XCC_ID)" : "=s"(xcc));
        sh_rank = __hip_atomic_fetch_add(&ctrl[xcc & 7u], 1u, __ATOMIC_RELAXED,
                                         __HIP_MEMORY_SCOPE_AGENT);
    }
    __syncthreads();
    const unsigned rank = sh_rank;
    if (rank >= 32u) return;              // uniform per WG

    const int wv   = tid >> 6;            // wave 0..7
    const int lane = tid & 63;
    const int c    = tid & 31;            // column-chunk selector 0..31
    const int jl   = tid >> 5;            // 0..15
    const int j    = (int)rank * 16 + jl; // 0..511

    // -- recurrent weights: 48 floats/thread -> resident VGPRs (r10-proven) --
    const float* wrp = w_hh + (size_t)j * HDIM + 4*c;
    const float* wzp = w_hh + (size_t)(HDIM   + j) * HDIM + 4*c;
    const float* wnp = w_hh + (size_t)(2*HDIM + j) * HDIM + 4*c;
    LDW(R, wrp, 0) LDW(R, wrp, 1) LDW(R, wrp, 2) LDW(R, wrp, 3)
    LDW(Z, wzp, 0) LDW(Z, wzp, 1) LDW(Z, wzp, 2) LDW(Z, wzp, 3)
    LDW(N, wnp, 0) LDW(N, wnp, 1) LDW(N, wnp, 2) LDW(N, wnp, 3)
    PINW(R,0) PINW(R,1) PINW(R,2) PINW(R,3)
    PINW(Z,0) PINW(Z,1) PINW(Z,2) PINW(Z,3)
    PINW(N,0) PINW(N,1) PINW(N,2) PINW(N,3)

    float bhr = b_hh[j], bhz = b_hh[HDIM + j], bhn = b_hh[2*HDIM + j];
    asm volatile("" : "+v"(bhr), "+v"(bhz), "+v"(bhn));

    // xg pipeline register (t=0 filled here, re-filled each step)
    float xr_c = 0.f, xz_c = 0.f, xn_c = 0.f;
    if (c == 0){ xr_c = xg[j]; xz_c = xg[HDIM + j]; xn_c = xg[2*HDIM + j]; }

    #pragma unroll 1
    for (int t = 0; t < T_STEPS; ++t){
        // ---- detect h_t ready: NT-poll the row itself (detect == stage) ----
        const float4* myp = (const float4*)(hs + (size_t)t * HDIM) + lane;
        float4 va, vb;
        int spins = 0;
        for (;;){
            asm volatile("global_load_dwordx4 %0, %2, off nt\n\t"
                         "global_load_dwordx4 %1, %2, off offset:1024 nt\n\t"
                         "s_waitcnt vmcnt(0)"
                         : "=&v"(va), "=&v"(vb) : "v"(myp) : "memory");
            int ok = (__float_as_uint(va.x) != SENT_U) & (__float_as_uint(va.y) != SENT_U)
                   & (__float_as_uint(va.z) != SENT_U) & (__float_as_uint(va.w) != SENT_U)
                   & (__float_as_uint(vb.x) != SENT_U) & (__float_as_uint(vb.y) != SENT_U)
                   & (__float_as_uint(vb.z) != SENT_U) & (__float_as_uint(vb.w) != SENT_U);
            if (__all(ok)) break;         // wave-uniform
            if (++spins > 5000) return;   // wave-uniform timeout (dead cluster)
        }

        // ---- issue next step's xg loads (landed by end-of-loop vmcnt) ----
        float xr_n = 0.f, xz_n = 0.f, xn_n = 0.f;
        if (c == 0 && t + 1 < T_STEPS){
            const float* xgn = xg + (size_t)(t + 1) * (3*HDIM);
            xr_n = xgn[j]; xz_n = xgn[HDIM + j]; xn_n = xgn[2*HDIM + j];
        }

        // ---- stage to this wave's LDS row (contiguous 16B/lane) ----
        *(float4*)&hbuf[wv][4 * lane]       = va;
        *(float4*)&hbuf[wv][256 + 4 * lane] = vb;
        asm volatile("s_waitcnt lgkmcnt(0)" ::: "memory");
        __builtin_amdgcn_sched_barrier(0);

        // ---- partial matvec: 48 FMAs/lane, 3 chains; reduce over c=0..31 ----
        float ar = 0.f, az = 0.f, an = 0.f;
        GSTEP(0) GSTEP(1) GSTEP(2) GSTEP(3)
        #pragma unroll
        for (int m = 1; m < 32; m <<= 1){
            ar += __shfl_xor(ar, m);
            az += __shfl_xor(az, m);
            an += __shfl_xor(an, m);
        }

        if (c == 0){
            const float r  = 1.0f / (1.0f + __expf(-(xr_c + ar + bhr)));
            const float z  = 1.0f / (1.0f + __expf(-(xz_c + az + bhz)));
            const float nn = xn_c + r * (an + bhn);
            const float e  = __expf(2.0f * nn);
            const float th = 1.0f - 2.0f / (e + 1.0f);   // tanh, inf-safe
            const float hnew = (1.0f - z) * th + z * hbuf[wv][j];
            hs[(size_t)(t + 1) * HDIM + j] = hnew;   // write-through store IS the flag
        }
        // drain the h-store to L2 NOW (visibility clock starts in our slack)
        // and land the xg prefetch so the next poll inherits nothing.
        asm volatile("s_waitcnt vmcnt(0)" ::: "memory");

        xr_c = xr_n; xz_c = xz_n; xn_c = xn_n;
    }
}

// ---------------------------------------------------------------------------
// Kernel 4: preds = hs[1..1024] @ w_pred^T + b_pred  (bf16 MFMA, fp32 out)
// ---------------------------------------------------------------------------
__launch_bounds__(256)
__global__ void pred_gemm_kernel(const float* __restrict__ hs, const float* __restrict__ w_pred,
                                 const float* __restrict__ b_pred, float* __restrict__ out){
    __shared__ unsigned short As[128 * 32];
    __shared__ unsigned short Bs[128 * 32];
    const int tid   = threadIdx.x;
    const int mtile = blockIdx.x;    // 0..7
    const int ntile = blockIdx.y;    // 0..226
    const int row  = tid >> 1, half = tid & 1;
    const int wave = tid >> 6, lane = tid & 63;
    const int wm = wave >> 1, wn = wave & 1;
    const int lr = lane & 15, kq = lane >> 4;

    f32x4 acc[4][4] = {};

    const float* Abase = hs + HDIM /*skip h0 row*/ + (size_t)(mtile * 128 + row) * HDIM;
    const int    nrow  = ntile * 128 + row;
    const float* Bbase = w_pred + (size_t)nrow * HDIM;

    for (int k0 = 0; k0 < HDIM; k0 += 32){
        {
            const float* srcp = Abase + k0 + half * 16;
            unsigned short* dst = &As[row * 32 + half * 16];
            #pragma unroll
            for (int q = 0; q < 4; ++q){
                float4 v = *(const float4*)(srcp + 4 * q);
                uint2 p;
                p.x = (unsigned)f2bf(v.x) | ((unsigned)f2bf(v.y) << 16);
                p.y = (unsigned)f2bf(v.z) | ((unsigned)f2bf(v.w) << 16);
                *(uint2*)(dst + 4 * q) = p;
            }
        }
        {
            unsigned short* dst = &Bs[row * 32 + half * 16];
            if (nrow < VOCAB){
                const float* srcp = Bbase + k0 + half * 16;
                #pragma unroll
                for (int q = 0; q < 4; ++q){
                    float4 v = *(const float4*)(srcp + 4 * q);
                    uint2 p;
                    p.x = (unsigned)f2bf(v.x) | ((unsigned)f2bf(v.y) << 16);
                    p.y = (unsigned)f2bf(v.z) | ((unsigned)f2bf(v.w) << 16);
                    *(uint2*)(dst + 4 * q) = p;
                }
            } else {
                uint2 zz; zz.x = 0u; zz.y = 0u;
                #pragma unroll
                for (int q = 0; q < 4; ++q) *(uint2*)(dst + 4 * q) = zz;
            }
        }
        __syncthreads();

        const unsigned short* Ab = &As[(wm * 64 + lr) * 32 + kq * 8];
        const unsigned short* Bb = &Bs[(wn * 64 + lr) * 32 + kq * 8];
        s16x8 af[4], bf[4];
        #pragma unroll
        for (int mf = 0; mf < 4; ++mf) af[mf] = *(const s16x8*)(Ab + mf * 16 * 32);
        #pragma unroll
        for (int nf = 0; nf < 4; ++nf) bf[nf] = *(const s16x8*)(Bb + nf * 16 * 32);
        #pragma unroll
        for (int mf = 0; mf < 4; ++mf){
            #pragma unroll
            for (int nf = 0; nf < 4; ++nf){
                acc[mf][nf] = __builtin_amdgcn_mfma_f32_16x16x32_bf16(af[mf], bf[nf], acc[mf][nf], 0, 0, 0);
            }
        }
        __syncthreads();
    }

    #pragma unroll
    for (int nf = 0; nf < 4; ++nf){
        const int n = ntile * 128 + wn * 64 + nf * 16 + lr;
        if (n >= VOCAB) continue;
        const float bp = b_pred[n];
        #pragma unroll
        for (int mf = 0; mf < 4; ++mf){
            const int m = mtile * 128 + wm * 64 + mf * 16 + kq * 4;
            #pragma unroll
            for (int q = 0; q < 4; ++q){
                out[(size_t)(m + q) * VOCAB + n] = acc[mf][nf][q] + bp;
            }
        }
    }
}

// ---------------------------------------------------------------------------
extern "C" void kernel_launch(void* const* d_in, const int* in_sizes, int n_in,
                              void* d_out, int out_size, void* d_ws, size_t ws_size,
                              hipStream_t stream){
    const float* x      = (const float*)d_in[0];
    const float* h0     = (const float*)d_in[1];
    const float* w_ih   = (const float*)d_in[2];
    const float* w_hh   = (const float*)d_in[3];
    const float* b_ih   = (const float*)d_in[4];
    const float* b_hh   = (const float*)d_in[5];
    const float* w_pred = (const float*)d_in[6];
    const float* b_pred = (const float*)d_in[7];
    float* out = (float*)d_out;

    float*    xg   = (float*)d_ws;                        // 1024*1536 fp32
    float*    hs   = xg + (size_t)T_STEPS * (3*HDIM);     // 1025*512  fp32
    unsigned* ctrl = (unsigned*)(hs + (size_t)(T_STEPS+1) * HDIM);  // 8 u32

    hipLaunchKernelGGL(init_hs_kernel, dim3(T_STEPS + 1), dim3(HDIM), 0, stream, h0, hs, ctrl);
    hipLaunchKernelGGL(xg_kernel,      dim3(6, 128),      dim3(256),  0, stream, x, w_ih, b_ih, xg);
    hipLaunchKernelGGL(scan_kernel,    dim3(256),         dim3(512),  0, stream, xg, w_hh, b_hh, hs, ctrl);
    hipLaunchKernelGGL(pred_gemm_kernel, dim3(8, 227),    dim3(256),  0, stream, hs, w_pred, b_pred, out);
}